// Round 11
// baseline (509.011 us; speedup 1.0000x reference)
//
#include <hip/hip_runtime.h>
#include <math.h>

#define D 128
#define HD 256
#define N_ENT 100000
#define NBATCH 64
#define NTOT (N_ENT + NBATCH)   // 100064
#define RCOUNT 500
#define E_BASE 400000
#define ETOT (E_BASE + N_ENT)   // 500000
#define NEG 0.2f
#define SCAN_NB 391             // 391*256 = 100096 (counts padded)
#define CPAD (SCAN_NB * 256)

#define WCAST_NB 64             // prep = Wbf cast only
#define REL_NB (RCOUNT + 1)

#define GEMM_NB ((NTOT + 63) / 64)              // 1564
#define HIST_NB ((ETOT + 255) / 256)            // 1954
#define EDGE_NB 6250                            // 25000 waves x 4 targets = 100000

typedef __attribute__((ext_vector_type(8))) short bf16x8;
typedef __attribute__((ext_vector_type(8))) unsigned short u16x8;
typedef __attribute__((ext_vector_type(4))) float f32x4;
typedef __attribute__((ext_vector_type(2))) float f32x2;

// hardware packed fp32->bf16 RNE (gfx950 v_cvt_pk_bf16_f32): lo -> [15:0], hi -> [31:16]
static __device__ __forceinline__ unsigned cvt_pk_bf16(float lo, float hi) {
  unsigned r;
  asm("v_cvt_pk_bf16_f32 %0, %1, %2" : "=v"(r) : "v"(lo), "v"(hi));
  return r;
}
static __device__ __forceinline__ unsigned short f2bf_hw(float f) {
  unsigned r;
  asm("v_cvt_pk_bf16_f32 %0, %1, %1" : "=v"(r) : "v"(f));
  return (unsigned short)r;
}
// decode 2 packed bf16 (one u32) -> 2 f32: 2 bit-ops total
static __device__ __forceinline__ f32x2 bfpair(unsigned u) {
  f32x2 r;
  r[0] = __builtin_bit_cast(float, u << 16);
  r[1] = __builtin_bit_cast(float, u & 0xffff0000u);
  return r;
}

// LDS-only barrier: syncs waves + drains LDS ops, but does NOT drain vmcnt --
// global stores stay in flight (HIP __syncthreads forces s_waitcnt vmcnt(0)).
static __device__ __forceinline__ void lds_barrier() {
  __builtin_amdgcn_sched_barrier(0);
  asm volatile("s_waitcnt lgkmcnt(0)" ::: "memory");
  __builtin_amdgcn_sched_barrier(0);
  __builtin_amdgcn_s_barrier();
  __builtin_amdgcn_sched_barrier(0);
}

// sum across each 16-lane row via DPP (bitwise-identical butterfly to shfl_xor 1/2/4/8):
// all full-rate VALU, no LDS.
static __device__ __forceinline__ float dpp_red16(float p) {
  int t;
  t = __builtin_amdgcn_update_dpp(0, __builtin_bit_cast(int, p), 0xB1, 0xF, 0xF, true);
  p += __builtin_bit_cast(float, t);
  t = __builtin_amdgcn_update_dpp(0, __builtin_bit_cast(int, p), 0x4E, 0xF, 0xF, true);
  p += __builtin_bit_cast(float, t);
  t = __builtin_amdgcn_update_dpp(0, __builtin_bit_cast(int, p), 0x141, 0xF, 0xF, true);
  p += __builtin_bit_cast(float, t);
  t = __builtin_amdgcn_update_dpp(0, __builtin_bit_cast(int, p), 0x140, 0xF, 0xF, true);
  p += __builtin_bit_cast(float, t);
  return p;
}

// ---------------- prep: Wbf cast only (64 blocks; serial prefix kept minimal) ----------------
__global__ __launch_bounds__(256) void k_prep(
    const float* __restrict__ W_l, const float* __restrict__ W_r,
    unsigned short* __restrict__ Wbf) {
  int e4 = (blockIdx.x * 256 + threadIdx.x) * 4;
  int v = e4 >> 7;          // virtual row 0..511
  int k = e4 & 127;
  const float* src = (v < HD) ? (W_l + (size_t)v * D + k) : (W_r + (size_t)(v - HD) * D + k);
  float4 a = *(const float4*)src;
  uint2 p;
  p.x = cvt_pk_bf16(a.x, a.y);
  p.y = cvt_pk_bf16(a.z, a.w);
  *(uint2*)(Wbf + (size_t)v * D + k) = p;
}

// ---------------- MFMA GEMM + fused edge histogram(+bsum) + fused e_rel/out_edge ----------------
#define LDA 136  // LDS row stride in ushort

__global__ __launch_bounds__(256) void k_gemm_mfma(
    const float* __restrict__ entities, const float* __restrict__ queries,
    const unsigned short* __restrict__ Wbf,
    const float* __restrict__ b_l, const float* __restrict__ b_r,
    unsigned short* __restrict__ x_l, unsigned short* __restrict__ x_r,
    const int* __restrict__ edge_index, const int* __restrict__ relation_index,
    const int* __restrict__ batch, int* __restrict__ counts, int* __restrict__ bsum,
    unsigned* __restrict__ tr, unsigned* __restrict__ key,
    const float* __restrict__ relations, const float* __restrict__ W_ea,
    const float* __restrict__ W_le, const float* __restrict__ b_le,
    unsigned short* __restrict__ e_rel, float* __restrict__ out_edge) {
  // single 17.4 KB buffer: stage-A tile, then (after afr hoist) reused as C staging.
  __shared__ unsigned short AsCs[64 * LDA];
  int tid = threadIdx.x;
  if (blockIdx.x >= GEMM_NB + HIST_NB) {   // rel blocks: e_rel + out_edge (independent work)
    float* relu_p = (float*)AsCs;          // alias gemm's LDS buffer
    int r = blockIdx.x - (GEMM_NB + HIST_NB);   // 0..500
    int j = tid;
    const float* w = W_ea + (size_t)j * D;
    float acc = 0.f;
    if (r < RCOUNT) {
      const float* rel = relations + (size_t)r * D;
      for (int k = 0; k < D; k += 4) {
        float4 a = *(const float4*)(rel + k);
        float4 b = *(const float4*)(w + k);
        acc += a.x * b.x + a.y * b.y + a.z * b.z + a.w * b.w;
      }
    } else {  // all-ones rel_feat row -> row sums of W_ea
      for (int k = 0; k < D; k += 4) {
        float4 b = *(const float4*)(w + k);
        acc += b.x + b.y + b.z + b.w;
      }
    }
    e_rel[(size_t)r * HD + j] = f2bf_hw(acc);
    if (r < RCOUNT) {
      relu_p[j] = acc > 0.f ? acc : 0.f;
      __syncthreads();
      if (j < D) {
        const float* wl = W_le + (size_t)j * HD;
        float o = b_le[j];
        for (int k = 0; k < HD; k += 4) {
          float4 p4 = *(const float4*)(relu_p + k);
          float4 w4 = *(const float4*)(wl + k);
          o += p4.x * w4.x + p4.y * w4.y + p4.z * w4.z + p4.w * w4.w;
        }
        out_edge[(size_t)r * D + j] = o;
      }
    }
    return;
  }
  if (blockIdx.x >= GEMM_NB) {   // histogram blocks: counts + bsum + (t,rank) and (s,r) packs
    int e = (blockIdx.x - GEMM_NB) * 256 + tid;
    if (e < ETOT) {
      int s, t, r;
      if (e < E_BASE) {
        s = edge_index[e];
        t = edge_index[E_BASE + e];
        r = relation_index[e];
      } else {
        int i = e - E_BASE;
        s = N_ENT + batch[i];
        t = i;
        r = RCOUNT;
      }
      int rk = atomicAdd(counts + t, 1);
      atomicAdd(bsum + (t >> 8), 1);   // block sums for the scan -> k_scan_a eliminated
      tr[e] = (unsigned)t | ((unsigned)rk << 17);
      key[e] = (unsigned)s | ((unsigned)r << 17);
    }
    return;
  }
  int rb = blockIdx.x;          // 64-row tile

  // ---- stage A (fp32 -> bf16 via v_cvt_pk, plain cached loads), once ----
  {
    int rr = tid >> 2;                 // 0..63
    int part = (tid & 3) * 32;
    int row = rb * 64 + rr;
    const float* sp;
    if (row < N_ENT) sp = entities + (size_t)row * D;
    else if (row < NTOT) sp = queries + (size_t)(row - N_ENT) * D;
    else sp = entities;  // dummy; stores guarded
#pragma unroll
    for (int k = 0; k < 32; k += 8) {
      float4 a0 = *(const float4*)(sp + part + k);
      float4 a1 = *(const float4*)(sp + part + k + 4);
      uint4 p;
      p.x = cvt_pk_bf16(a0.x, a0.y);
      p.y = cvt_pk_bf16(a0.z, a0.w);
      p.z = cvt_pk_bf16(a1.x, a1.y);
      p.w = cvt_pk_bf16(a1.z, a1.w);
      *(uint4*)(&AsCs[rr * LDA + part + k]) = p;
    }
  }
  __syncthreads();

  int w = tid >> 6, lane = tid & 63;
  int wr = w >> 1, wc = w & 1;          // 2x2 wave grid per 128-col chunk
  int m = lane & 15, q8 = (lane >> 4) * 8;

  // ---- hoist A fragments to registers: after this, the LDS tile is DEAD as A ----
  bf16x8 afr[4][2];
#pragma unroll
  for (int k4 = 0; k4 < 4; k4++)
#pragma unroll
    for (int i = 0; i < 2; i++)
      afr[k4][i] = *(const bf16x8*)(&AsCs[(wr * 32 + i * 16 + m) * LDA + k4 * 32 + q8]);

  for (int ccv = 0; ccv < 4; ccv++) {   // virtual col chunks of 128 (0,1->x_l; 2,3->x_r)
    bool isL = ccv < 2;
    const float* bv = isL ? b_l : b_r;
    unsigned short* xdst = isL ? x_l : x_r;
    int cbase = (ccv & 1) * 128;

    f32x4 acc[2][4];
#pragma unroll
    for (int i = 0; i < 2; i++)
#pragma unroll
      for (int j = 0; j < 4; j++) acc[i][j] = (f32x4){0.f, 0.f, 0.f, 0.f};

    const unsigned short* wbase = Wbf + (size_t)(ccv * 128 + wc * 64 + m) * D;
#pragma unroll
    for (int k4 = 0; k4 < 4; k4++) {
      bf16x8 bfr[4];
#pragma unroll
      for (int j = 0; j < 4; j++)
        bfr[j] = *(const bf16x8*)(wbase + (size_t)j * 16 * D + k4 * 32 + q8);
#pragma unroll
      for (int i = 0; i < 2; i++)
#pragma unroll
        for (int j = 0; j < 4; j++)
          acc[i][j] = __builtin_amdgcn_mfma_f32_16x16x32_bf16(afr[k4][i], bfr[j], acc[i][j], 0, 0, 0);
    }

    // all waves' afr hoist reads (and prior chunk's C ds_reads) complete before
    // overwriting the buffer; global stores stay in flight (no vmcnt drain).
    lds_barrier();
    // acc -> LDS (row-major, +bias, bf16). C layout: col=lane&15, row=(lane>>4)*4+reg
#pragma unroll
    for (int j = 0; j < 4; j++) {
      int col = wc * 64 + j * 16 + m;
      float bb = bv[cbase + col];
#pragma unroll
      for (int i = 0; i < 2; i++) {
        int row0 = wr * 32 + i * 16 + (lane >> 4) * 4;
#pragma unroll
        for (int r = 0; r < 4; r++)
          AsCs[(row0 + r) * LDA + col] = f2bf_hw(acc[i][j][r] + bb);
      }
    }
    lds_barrier();  // C ds_writes visible to all waves
    // coalesced CACHED global store (R6: x_l/x_r LLC residency feeds k_edge's gathers)
#pragma unroll
    for (int it = 0; it < 4; it++) {
      int g = it * 256 + tid;
      int row = g >> 4, c8 = (g & 15) * 8;
      int grow = rb * 64 + row;
      if (grow < NTOT) {
        u16x8 v = *(const u16x8*)(&AsCs[row * LDA + c8]);
        *(u16x8*)(xdst + (size_t)grow * HD + cbase + c8) = v;
      }
    }
  }
}

// ---------------- scan: lookback over bsum + local scan -> offsets ----------------
__global__ __launch_bounds__(256) void k_scan(
    const int* __restrict__ counts, const int* __restrict__ bsum,
    int* __restrict__ offsets) {
  __shared__ int s[256];
  int b = blockIdx.x, tid = threadIdx.x;
  int part = 0;
  if (tid < b) part += bsum[tid];
  if (tid + 256 < b) part += bsum[tid + 256];
  s[tid] = part;
  __syncthreads();
  for (int off = 128; off > 0; off >>= 1) {
    if (tid < off) s[tid] += s[tid + off];
    __syncthreads();
  }
  int pre_sum = s[0];
  __syncthreads();
  int v = counts[b * 256 + tid];
  s[tid] = v;
  __syncthreads();
  for (int off = 1; off < 256; off <<= 1) {
    int y = (tid >= off) ? s[tid - off] : 0;
    __syncthreads();
    s[tid] += y;
    __syncthreads();
  }
  int excl = pre_sum + s[tid] - v;
  int i = b * 256 + tid;
  if (i <= N_ENT) offsets[i] = excl;   // i==N_ENT -> ETOT
}

// atomic-free scatter, pure copy: pos = offsets[t] + rank, both packed in tr[e]
__global__ void k_scatter(const unsigned* __restrict__ tr, const unsigned* __restrict__ key,
                          const int* __restrict__ offsets, unsigned* __restrict__ sorted) {
  int e = blockIdx.x * 256 + threadIdx.x;
  if (e >= ETOT) return;
  unsigned a = tr[e];
  sorted[offsets[a & 0x1FFFFu] + (a >> 17)] = key[e];
}

// one edge's elementwise work on this lane's 8 elems (4 f32-pairs -> v_pk_* ops):
// returns lane-partial logit; writes decoded x_l pair values for the later acc FMA.
static __device__ __forceinline__ float edge_accum(
    u16x8 xl8, u16x8 er8, const f32x2* __restrict__ xr2,
    const f32x2* __restrict__ at2, f32x2* __restrict__ x2) {
  uint4 xu = __builtin_bit_cast(uint4, xl8);
  uint4 eu = __builtin_bit_cast(uint4, er8);
  unsigned xw[4] = {xu.x, xu.y, xu.z, xu.w};
  unsigned ew[4] = {eu.x, eu.y, eu.z, eu.w};
  f32x2 p2 = (f32x2){0.f, 0.f};
#pragma unroll
  for (int i = 0; i < 4; ++i) {
    f32x2 x = bfpair(xw[i]);
    x2[i] = x;
    f32x2 z = (x + xr2[i]) + bfpair(ew[i]);
    f32x2 zn = z * NEG;
    z[0] = fmaxf(z[0], zn[0]);   // leaky_relu(z) == max(z, 0.2z)
    z[1] = fmaxf(z[1], zn[1]);
    p2 += z * at2[i];
  }
  return p2[0] + p2[1];
}

// ---------------- per-target aggregate: persistent waves, 4 targets/wave ----------------
// lanes 0-31 edge e, lanes 32-63 edge e+1; within 32: sl 0-15 head0, sl 16-31 head1.
__global__ __launch_bounds__(256) void k_edge(
    const unsigned short* __restrict__ x_l, const unsigned short* __restrict__ x_r,
    const unsigned short* __restrict__ e_rel, const int* __restrict__ offsets,
    const unsigned* __restrict__ sorted, const float* __restrict__ att,
    const float* __restrict__ bias, float* __restrict__ out) {
  int wv = threadIdx.x >> 6;
  int lane = threadIdx.x & 63;
  int half = lane >> 5;         // which edge of the pair
  int sl = lane & 31;
  int elem = sl * 8;            // head = sl>>4
  int t0 = (blockIdx.x * 4 + wv) * 4;   // 4 contiguous targets per wave

  const char* xlb = (const char*)x_l + elem * 2;   // per-lane gather bases
  const char* erb = (const char*)e_rel + elem * 2;

  f32x2 at2[4];
  {
    float4 a0 = *(const float4*)(att + elem);
    float4 a1 = *(const float4*)(att + elem + 4);
    at2[0] = (f32x2){a0.x, a0.y};
    at2[1] = (f32x2){a0.z, a0.w};
    at2[2] = (f32x2){a1.x, a1.y};
    at2[3] = (f32x2){a1.z, a1.w};
  }
  // all 5 edge-range boundaries for this wave in one 16B load + 1 scalar
  int4 ofs = *(const int4*)(offsets + t0);
  int eb[5];
  eb[0] = ofs.x; eb[1] = ofs.y; eb[2] = ofs.z; eb[3] = ofs.w;
  eb[4] = offsets[t0 + 4];

  u16x8 xr8 = __builtin_nontemporal_load((const u16x8*)(x_r + (size_t)t0 * HD + elem));

#pragma unroll
  for (int ti = 0; ti < 4; ++ti) {
    f32x2 xr2[4];
    {
      uint4 u = __builtin_bit_cast(uint4, xr8);
      xr2[0] = bfpair(u.x); xr2[1] = bfpair(u.y);
      xr2[2] = bfpair(u.z); xr2[3] = bfpair(u.w);
    }
    // prefetch next target's x_r row (t0+ti+1 <= 100000 < NTOT, always in-bounds)
    xr8 = __builtin_nontemporal_load((const u16x8*)(x_r + (size_t)(t0 + ti + 1) * HD + elem));

    int e0 = eb[ti], e1 = eb[ti + 1];
    f32x2 acc2[4];
    acc2[0] = acc2[1] = acc2[2] = acc2[3] = (f32x2){0.f, 0.f};
    float denom = 0.f;
    int e = e0;
    // ---- main: 4 valid edges per iter, two independent chains, no guards ----
    for (; e + 4 <= e1; e += 4) {
      unsigned srA = sorted[e + half];
      unsigned srB = sorted[e + 2 + half];
      u16x8 xlA = *(const u16x8*)(xlb + ((size_t)(srA & 0x1FFFFu) << 9));
      u16x8 erA = *(const u16x8*)(erb + ((size_t)(srA >> 17) << 9));
      u16x8 xlB = *(const u16x8*)(xlb + ((size_t)(srB & 0x1FFFFu) << 9));
      u16x8 erB = *(const u16x8*)(erb + ((size_t)(srB >> 17) << 9));
      f32x2 xa2[4], xb2[4];
      float pa = edge_accum(xlA, erA, xr2, at2, xa2);
      float pb = edge_accum(xlB, erB, xr2, at2, xb2);
      pa = dpp_red16(pa);
      pb = dpp_red16(pb);
      float wa = __expf(pa);
      float wb = __expf(pb);
      denom += wa + wb;
#pragma unroll
      for (int i = 0; i < 4; ++i) {
        acc2[i] += xa2[i] * wa;     // v_pk_fma_f32
        acc2[i] += xb2[i] * wb;
      }
    }
    // ---- tail: guarded pairs (at most 2 iterations) ----
    for (; e < e1; e += 2) {
      int ee = e + half;
      bool valid = ee < e1;
      unsigned sr = sorted[valid ? ee : e0];
      u16x8 xl8 = *(const u16x8*)(xlb + ((size_t)(sr & 0x1FFFFu) << 9));
      u16x8 er8 = *(const u16x8*)(erb + ((size_t)(sr >> 17) << 9));
      f32x2 x2[4];
      float p = edge_accum(xl8, er8, xr2, at2, x2);
      p = dpp_red16(p);
      float wgt = valid ? __expf(p) : 0.f;
      denom += wgt;
#pragma unroll
      for (int i = 0; i < 4; ++i) acc2[i] += x2[i] * wgt;
    }
    // combine the two edge-halves (same target, same head layout)
    denom += __shfl_xor(denom, 32, 64);
#pragma unroll
    for (int i = 0; i < 4; ++i) {
      acc2[i][0] += __shfl_xor(acc2[i][0], 32, 64);
      acc2[i][1] += __shfl_xor(acc2[i][1], 32, 64);
    }
    // normalize per head; fold the head-mean (x0.5) into the reciprocal
    float inv = 0.5f / (denom + 1e-16f);
    float o[8];
#pragma unroll
    for (int i = 0; i < 4; ++i) {
      o[2 * i] = acc2[i][0] * inv;
      o[2 * i + 1] = acc2[i][1] * inv;
    }
    // combine heads: lane sl (head0, d=8sl..) with lane sl^16 (head1, same d)
#pragma unroll
    for (int i = 0; i < 8; ++i) o[i] += __shfl_xor(o[i], 16, 64);
    if (lane < 16) {
      int t = t0 + ti;
      int d = sl * 8;
      float4 b0 = *(const float4*)(bias + d);
      float4 b1 = *(const float4*)(bias + d + 4);
      f32x4 s0 = (f32x4){o[0] + b0.x, o[1] + b0.y, o[2] + b0.z, o[3] + b0.w};
      f32x4 s1 = (f32x4){o[4] + b1.x, o[5] + b1.y, o[6] + b1.z, o[7] + b1.w};
      __builtin_nontemporal_store(s0, (f32x4*)(out + (size_t)t * D + d));
      __builtin_nontemporal_store(s1, (f32x4*)(out + (size_t)t * D + d + 4));
    }
  }
}

extern "C" void kernel_launch(void* const* d_in, const int* in_sizes, int n_in,
                              void* d_out, int out_size, void* d_ws, size_t ws_size,
                              hipStream_t stream) {
  const float* queries = (const float*)d_in[0];
  const float* entities = (const float*)d_in[1];
  const int* edge_index = (const int*)d_in[2];
  const float* relations = (const float*)d_in[3];
  const int* relation_index = (const int*)d_in[4];
  const int* batch = (const int*)d_in[5];
  const float* W_l = (const float*)d_in[6];
  const float* b_l = (const float*)d_in[7];
  const float* W_r = (const float*)d_in[8];
  const float* b_r = (const float*)d_in[9];
  const float* W_ea = (const float*)d_in[10];
  const float* att = (const float*)d_in[11];
  const float* bias = (const float*)d_in[12];
  const float* W_le = (const float*)d_in[13];
  const float* b_le = (const float*)d_in[14];

  float* out_node = (float*)d_out;
  float* out_edge = out_node + (size_t)N_ENT * D;

  char* base = (char*)d_ws;
  size_t off = 0;
  auto take = [&](size_t nbytes) -> void* {
    void* p = base + off;
    off += (nbytes + 255) & ~(size_t)255;
    return p;
  };
  unsigned short* x_l = (unsigned short*)take((size_t)NTOT * HD * sizeof(unsigned short)); // 51.2 MB
  unsigned short* x_r = (unsigned short*)take((size_t)NTOT * HD * sizeof(unsigned short)); // 51.2 MB
  unsigned short* e_rel = (unsigned short*)take((size_t)(RCOUNT + 1) * HD * sizeof(unsigned short));
  unsigned short* Wbf = (unsigned short*)take((size_t)512 * D * sizeof(unsigned short));   // 128 KB
  int* counts = (int*)take((size_t)(CPAD + 512) * sizeof(int));   // counts + bsum, one memset
  int* bsum = counts + CPAD;                                      // CPAD*4 is 256B-aligned
  int* offsets = (int*)take((size_t)(N_ENT + 1) * sizeof(int));
  unsigned* tr = (unsigned*)take((size_t)ETOT * sizeof(unsigned));                         // 2 MB
  unsigned* key = (unsigned*)take((size_t)ETOT * sizeof(unsigned));                        // 2 MB
  unsigned* sorted = (unsigned*)take((size_t)ETOT * sizeof(unsigned));                     // 2 MB

  hipMemsetAsync(counts, 0, (size_t)(CPAD + 512) * sizeof(int), stream);
  k_prep<<<dim3(WCAST_NB), dim3(256), 0, stream>>>(W_l, W_r, Wbf);
  k_gemm_mfma<<<dim3(GEMM_NB + HIST_NB + REL_NB), dim3(256), 0, stream>>>(
      entities, queries, Wbf, b_l, b_r, x_l, x_r, edge_index, relation_index, batch,
      counts, bsum, tr, key, relations, W_ea, W_le, b_le, e_rel, out_edge);
  k_scan<<<dim3(SCAN_NB), dim3(256), 0, stream>>>(counts, bsum, offsets);
  k_scatter<<<dim3(HIST_NB), dim3(256), 0, stream>>>(tr, key, offsets, sorted);
  k_edge<<<dim3(EDGE_NB), dim3(256), 0, stream>>>(x_l, x_r, e_rel, offsets, sorted, att, bias, out_node);
}

// Round 13
// 285.243 us; speedup vs baseline: 1.7845x; 1.7845x over previous
//
#include <hip/hip_runtime.h>
#include <math.h>

#define D 128
#define HD 256
#define N_ENT 100000
#define NBATCH 64
#define NTOT (N_ENT + NBATCH)   // 100064
#define RCOUNT 500
#define E_BASE 400000
#define ETOT (E_BASE + N_ENT)   // 500000
#define NEG 0.2f
#define SCAN_NB 391             // 391*256 = 100096 (counts padded)
#define CPAD (SCAN_NB * 256)

#define WCAST_NB 64
#define REL_NB (RCOUNT + 1)
#define PREP_NB (WCAST_NB + REL_NB)             // 565

#define GEMM_NB ((NTOT + 63) / 64)              // 1564
#define HIST_NB ((ETOT + 255) / 256)            // 1954
#define EDGE_NB 6250                            // 25000 waves x 4 targets = 100000

typedef __attribute__((ext_vector_type(8))) short bf16x8;
typedef __attribute__((ext_vector_type(8))) unsigned short u16x8;
typedef __attribute__((ext_vector_type(4))) float f32x4;
typedef __attribute__((ext_vector_type(2))) float f32x2;

// hardware packed fp32->bf16 RNE (gfx950 v_cvt_pk_bf16_f32): lo -> [15:0], hi -> [31:16]
static __device__ __forceinline__ unsigned cvt_pk_bf16(float lo, float hi) {
  unsigned r;
  asm("v_cvt_pk_bf16_f32 %0, %1, %2" : "=v"(r) : "v"(lo), "v"(hi));
  return r;
}
static __device__ __forceinline__ unsigned short f2bf_hw(float f) {
  unsigned r;
  asm("v_cvt_pk_bf16_f32 %0, %1, %1" : "=v"(r) : "v"(f));
  return (unsigned short)r;
}
// decode 2 packed bf16 (one u32) -> 2 f32: 2 bit-ops total
static __device__ __forceinline__ f32x2 bfpair(unsigned u) {
  f32x2 r;
  r[0] = __builtin_bit_cast(float, u << 16);
  r[1] = __builtin_bit_cast(float, u & 0xffff0000u);
  return r;
}

// LDS-only barrier: syncs waves + drains LDS ops, but does NOT drain vmcnt --
// global stores stay in flight (HIP __syncthreads forces s_waitcnt vmcnt(0)).
static __device__ __forceinline__ void lds_barrier() {
  __builtin_amdgcn_sched_barrier(0);
  asm volatile("s_waitcnt lgkmcnt(0)" ::: "memory");
  __builtin_amdgcn_sched_barrier(0);
  __builtin_amdgcn_s_barrier();
  __builtin_amdgcn_sched_barrier(0);
}

// sum across each 16-lane row via DPP (bitwise-identical butterfly to shfl_xor 1/2/4/8):
// all full-rate VALU, no LDS.
static __device__ __forceinline__ float dpp_red16(float p) {
  int t;
  t = __builtin_amdgcn_update_dpp(0, __builtin_bit_cast(int, p), 0xB1, 0xF, 0xF, true);
  p += __builtin_bit_cast(float, t);
  t = __builtin_amdgcn_update_dpp(0, __builtin_bit_cast(int, p), 0x4E, 0xF, 0xF, true);
  p += __builtin_bit_cast(float, t);
  t = __builtin_amdgcn_update_dpp(0, __builtin_bit_cast(int, p), 0x141, 0xF, 0xF, true);
  p += __builtin_bit_cast(float, t);
  t = __builtin_amdgcn_update_dpp(0, __builtin_bit_cast(int, p), 0x140, 0xF, 0xF, true);
  p += __builtin_bit_cast(float, t);
  return p;
}

// ---------------- prep: Wbf cast | e_rel + out_edge ----------------
__global__ __launch_bounds__(256) void k_prep(
    const float* __restrict__ W_l, const float* __restrict__ W_r,
    unsigned short* __restrict__ Wbf,
    const float* __restrict__ relations, const float* __restrict__ W_ea,
    const float* __restrict__ W_le, const float* __restrict__ b_le,
    unsigned short* __restrict__ e_rel, float* __restrict__ out_edge) {
  __shared__ float relu_p[HD];
  int bx = blockIdx.x;
  int tid = threadIdx.x;
  if (bx < WCAST_NB) {
    int e4 = (bx * 256 + tid) * 4;
    int v = e4 >> 7;          // virtual row 0..511
    int k = e4 & 127;
    const float* src = (v < HD) ? (W_l + (size_t)v * D + k) : (W_r + (size_t)(v - HD) * D + k);
    float4 a = *(const float4*)src;
    uint2 p;
    p.x = cvt_pk_bf16(a.x, a.y);
    p.y = cvt_pk_bf16(a.z, a.w);
    *(uint2*)(Wbf + (size_t)v * D + k) = p;
    return;
  }
  int r = bx - WCAST_NB;   // 0..500
  int j = tid;
  const float* w = W_ea + (size_t)j * D;
  float acc = 0.f;
  if (r < RCOUNT) {
    const float* rel = relations + (size_t)r * D;
    for (int k = 0; k < D; k += 4) {
      float4 a = *(const float4*)(rel + k);
      float4 b = *(const float4*)(w + k);
      acc += a.x * b.x + a.y * b.y + a.z * b.z + a.w * b.w;
    }
  } else {  // all-ones rel_feat row -> row sums of W_ea
    for (int k = 0; k < D; k += 4) {
      float4 b = *(const float4*)(w + k);
      acc += b.x + b.y + b.z + b.w;
    }
  }
  e_rel[(size_t)r * HD + j] = f2bf_hw(acc);
  if (r < RCOUNT) {
    relu_p[j] = acc > 0.f ? acc : 0.f;
    __syncthreads();
    if (j < D) {
      const float* wl = W_le + (size_t)j * HD;
      float o = b_le[j];
      for (int k = 0; k < HD; k += 4) {
        float4 p4 = *(const float4*)(relu_p + k);
        float4 w4 = *(const float4*)(wl + k);
        o += p4.x * w4.x + p4.y * w4.y + p4.z * w4.z + p4.w * w4.w;
      }
      out_edge[(size_t)r * D + j] = o;
    }
  }
}

// ---------------- MFMA GEMM (64-row blocks, all 512 vcols) + fused edge histogram ----------------
#define LDA 136  // LDS row stride in ushort

__global__ __launch_bounds__(256) void k_gemm_mfma(
    const float* __restrict__ entities, const float* __restrict__ queries,
    const unsigned short* __restrict__ Wbf,
    const float* __restrict__ b_l, const float* __restrict__ b_r,
    unsigned short* __restrict__ x_l, unsigned short* __restrict__ x_r,
    const int* __restrict__ edge_index, const int* __restrict__ relation_index,
    const int* __restrict__ batch, int* __restrict__ counts,
    unsigned* __restrict__ tr, unsigned* __restrict__ key) {
  // single 17.4 KB buffer: stage-A tile, then (after afr hoist) reused as C staging.
  // halves LDS/block vs separate As/Cs -> 8 blocks/CU (wave cap) instead of 4.
  __shared__ unsigned short AsCs[64 * LDA];
  int tid = threadIdx.x;
  if (blockIdx.x >= GEMM_NB) {   // histogram blocks: count + per-edge (t,rank) and (s,r) packs
    int e = (blockIdx.x - GEMM_NB) * 256 + tid;
    if (e < ETOT) {
      int s, t, r;
      if (e < E_BASE) {
        s = edge_index[e];
        t = edge_index[E_BASE + e];
        r = relation_index[e];
      } else {
        int i = e - E_BASE;
        s = N_ENT + batch[i];
        t = i;
        r = RCOUNT;
      }
      int rk = atomicAdd(counts + t, 1);
      // NOTE (R11 lesson): do NOT add a second atomic to a low-cardinality array here.
      // 500K atomics -> 391 counters (~25 cache lines) line-serialize at L2: +240 us.
      tr[e] = (unsigned)t | ((unsigned)rk << 17);
      key[e] = (unsigned)s | ((unsigned)r << 17);
    }
    return;
  }
  int rb = blockIdx.x;          // 64-row tile

  // ---- stage A (fp32 -> bf16 via v_cvt_pk, plain cached loads), once ----
  {
    int rr = tid >> 2;                 // 0..63
    int part = (tid & 3) * 32;
    int row = rb * 64 + rr;
    const float* sp;
    if (row < N_ENT) sp = entities + (size_t)row * D;
    else if (row < NTOT) sp = queries + (size_t)(row - N_ENT) * D;
    else sp = entities;  // dummy; stores guarded
#pragma unroll
    for (int k = 0; k < 32; k += 8) {
      float4 a0 = *(const float4*)(sp + part + k);
      float4 a1 = *(const float4*)(sp + part + k + 4);
      uint4 p;
      p.x = cvt_pk_bf16(a0.x, a0.y);
      p.y = cvt_pk_bf16(a0.z, a0.w);
      p.z = cvt_pk_bf16(a1.x, a1.y);
      p.w = cvt_pk_bf16(a1.z, a1.w);
      *(uint4*)(&AsCs[rr * LDA + part + k]) = p;
    }
  }
  __syncthreads();

  int w = tid >> 6, lane = tid & 63;
  int wr = w >> 1, wc = w & 1;          // 2x2 wave grid per 128-col chunk
  int m = lane & 15, q8 = (lane >> 4) * 8;

  // ---- hoist A fragments to registers: after this, the LDS tile is DEAD as A ----
  bf16x8 afr[4][2];
#pragma unroll
  for (int k4 = 0; k4 < 4; k4++)
#pragma unroll
    for (int i = 0; i < 2; i++)
      afr[k4][i] = *(const bf16x8*)(&AsCs[(wr * 32 + i * 16 + m) * LDA + k4 * 32 + q8]);

  for (int ccv = 0; ccv < 4; ccv++) {   // virtual col chunks of 128 (0,1->x_l; 2,3->x_r)
    bool isL = ccv < 2;
    const float* bv = isL ? b_l : b_r;
    unsigned short* xdst = isL ? x_l : x_r;
    int cbase = (ccv & 1) * 128;

    f32x4 acc[2][4];
#pragma unroll
    for (int i = 0; i < 2; i++)
#pragma unroll
      for (int j = 0; j < 4; j++) acc[i][j] = (f32x4){0.f, 0.f, 0.f, 0.f};

    const unsigned short* wbase = Wbf + (size_t)(ccv * 128 + wc * 64 + m) * D;
#pragma unroll
    for (int k4 = 0; k4 < 4; k4++) {
      bf16x8 bfr[4];
#pragma unroll
      for (int j = 0; j < 4; j++)
        bfr[j] = *(const bf16x8*)(wbase + (size_t)j * 16 * D + k4 * 32 + q8);
#pragma unroll
      for (int i = 0; i < 2; i++)
#pragma unroll
        for (int j = 0; j < 4; j++)
          acc[i][j] = __builtin_amdgcn_mfma_f32_16x16x32_bf16(afr[k4][i], bfr[j], acc[i][j], 0, 0, 0);
    }

    // all waves' afr hoist reads (and prior chunk's C ds_reads) complete before
    // overwriting the buffer; global stores stay in flight (no vmcnt drain).
    lds_barrier();
    // acc -> LDS (row-major, +bias, bf16). C layout: col=lane&15, row=(lane>>4)*4+reg
#pragma unroll
    for (int j = 0; j < 4; j++) {
      int col = wc * 64 + j * 16 + m;
      float bb = bv[cbase + col];
#pragma unroll
      for (int i = 0; i < 2; i++) {
        int row0 = wr * 32 + i * 16 + (lane >> 4) * 4;
#pragma unroll
        for (int r = 0; r < 4; r++)
          AsCs[(row0 + r) * LDA + col] = f2bf_hw(acc[i][j][r] + bb);
      }
    }
    lds_barrier();  // C ds_writes visible to all waves
    // coalesced CACHED global store (R6: x_l/x_r LLC residency feeds k_edge's gathers)
#pragma unroll
    for (int it = 0; it < 4; it++) {
      int g = it * 256 + tid;
      int row = g >> 4, c8 = (g & 15) * 8;
      int grow = rb * 64 + row;
      if (grow < NTOT) {
        u16x8 v = *(const u16x8*)(&AsCs[row * LDA + c8]);
        *(u16x8*)(xdst + (size_t)grow * HD + cbase + c8) = v;
      }
    }
  }
}

// ---------------- scan part a: per-block sums of counts ----------------
__global__ __launch_bounds__(256) void k_scan_a(const int* __restrict__ counts, int* __restrict__ bsum) {
  __shared__ int sd[256];
  int tid = threadIdx.x;
  sd[tid] = counts[blockIdx.x * 256 + tid];
  __syncthreads();
  for (int off = 128; off > 0; off >>= 1) {
    if (tid < off) sd[tid] += sd[tid + off];
    __syncthreads();
  }
  if (tid == 0) bsum[blockIdx.x] = sd[0];
}

// ---------------- scan part b: lookback over bsum + local scan -> offsets ----------------
__global__ __launch_bounds__(256) void k_scan_b(
    const int* __restrict__ counts, const int* __restrict__ bsum,
    int* __restrict__ offsets) {
  __shared__ int s[256];
  int b = blockIdx.x, tid = threadIdx.x;
  int part = 0;
  if (tid < b) part += bsum[tid];
  if (tid + 256 < b) part += bsum[tid + 256];
  s[tid] = part;
  __syncthreads();
  for (int off = 128; off > 0; off >>= 1) {
    if (tid < off) s[tid] += s[tid + off];
    __syncthreads();
  }
  int pre_sum = s[0];
  __syncthreads();
  int v = counts[b * 256 + tid];
  s[tid] = v;
  __syncthreads();
  for (int off = 1; off < 256; off <<= 1) {
    int y = (tid >= off) ? s[tid - off] : 0;
    __syncthreads();
    s[tid] += y;
    __syncthreads();
  }
  int excl = pre_sum + s[tid] - v;
  int i = b * 256 + tid;
  if (i <= N_ENT) offsets[i] = excl;   // i==N_ENT -> ETOT
}

// atomic-free scatter, pure copy: pos = offsets[t] + rank, both packed in tr[e]
__global__ void k_scatter(const unsigned* __restrict__ tr, const unsigned* __restrict__ key,
                          const int* __restrict__ offsets, unsigned* __restrict__ sorted) {
  int e = blockIdx.x * 256 + threadIdx.x;
  if (e >= ETOT) return;
  unsigned a = tr[e];
  sorted[offsets[a & 0x1FFFFu] + (a >> 17)] = key[e];
}

// one edge's elementwise work on this lane's 8 elems (4 f32-pairs -> v_pk_* ops):
// returns lane-partial logit; writes decoded x_l pair values for the later acc FMA.
static __device__ __forceinline__ float edge_accum(
    u16x8 xl8, u16x8 er8, const f32x2* __restrict__ xr2,
    const f32x2* __restrict__ at2, f32x2* __restrict__ x2) {
  uint4 xu = __builtin_bit_cast(uint4, xl8);
  uint4 eu = __builtin_bit_cast(uint4, er8);
  unsigned xw[4] = {xu.x, xu.y, xu.z, xu.w};
  unsigned ew[4] = {eu.x, eu.y, eu.z, eu.w};
  f32x2 p2 = (f32x2){0.f, 0.f};
#pragma unroll
  for (int i = 0; i < 4; ++i) {
    f32x2 x = bfpair(xw[i]);
    x2[i] = x;
    f32x2 z = (x + xr2[i]) + bfpair(ew[i]);
    f32x2 zn = z * NEG;
    z[0] = fmaxf(z[0], zn[0]);   // leaky_relu(z) == max(z, 0.2z)
    z[1] = fmaxf(z[1], zn[1]);
    p2 += z * at2[i];
  }
  return p2[0] + p2[1];
}

// ---------------- per-target aggregate: persistent waves, 4 targets/wave ----------------
// lanes 0-31 edge e, lanes 32-63 edge e+1; within 32: sl 0-15 head0, sl 16-31 head1.
__global__ __launch_bounds__(256) void k_edge(
    const unsigned short* __restrict__ x_l, const unsigned short* __restrict__ x_r,
    const unsigned short* __restrict__ e_rel, const int* __restrict__ offsets,
    const unsigned* __restrict__ sorted, const float* __restrict__ att,
    const float* __restrict__ bias, float* __restrict__ out) {
  int wv = threadIdx.x >> 6;
  int lane = threadIdx.x & 63;
  int half = lane >> 5;         // which edge of the pair
  int sl = lane & 31;
  int elem = sl * 8;            // head = sl>>4
  int t0 = (blockIdx.x * 4 + wv) * 4;   // 4 contiguous targets per wave

  const char* xlb = (const char*)x_l + elem * 2;   // per-lane gather bases
  const char* erb = (const char*)e_rel + elem * 2;

  f32x2 at2[4];
  {
    float4 a0 = *(const float4*)(att + elem);
    float4 a1 = *(const float4*)(att + elem + 4);
    at2[0] = (f32x2){a0.x, a0.y};
    at2[1] = (f32x2){a0.z, a0.w};
    at2[2] = (f32x2){a1.x, a1.y};
    at2[3] = (f32x2){a1.z, a1.w};
  }
  // all 5 edge-range boundaries for this wave in one 16B load + 1 scalar
  int4 ofs = *(const int4*)(offsets + t0);
  int eb[5];
  eb[0] = ofs.x; eb[1] = ofs.y; eb[2] = ofs.z; eb[3] = ofs.w;
  eb[4] = offsets[t0 + 4];

  u16x8 xr8 = __builtin_nontemporal_load((const u16x8*)(x_r + (size_t)t0 * HD + elem));

#pragma unroll
  for (int ti = 0; ti < 4; ++ti) {
    f32x2 xr2[4];
    {
      uint4 u = __builtin_bit_cast(uint4, xr8);
      xr2[0] = bfpair(u.x); xr2[1] = bfpair(u.y);
      xr2[2] = bfpair(u.z); xr2[3] = bfpair(u.w);
    }
    // prefetch next target's x_r row (t0+ti+1 <= 100000 < NTOT, always in-bounds)
    xr8 = __builtin_nontemporal_load((const u16x8*)(x_r + (size_t)(t0 + ti + 1) * HD + elem));

    int e0 = eb[ti], e1 = eb[ti + 1];
    f32x2 acc2[4];
    acc2[0] = acc2[1] = acc2[2] = acc2[3] = (f32x2){0.f, 0.f};
    float denom = 0.f;
    int e = e0;
    // ---- main: 4 valid edges per iter, two independent chains, no guards ----
    for (; e + 4 <= e1; e += 4) {
      unsigned srA = sorted[e + half];
      unsigned srB = sorted[e + 2 + half];
      u16x8 xlA = *(const u16x8*)(xlb + ((size_t)(srA & 0x1FFFFu) << 9));
      u16x8 erA = *(const u16x8*)(erb + ((size_t)(srA >> 17) << 9));
      u16x8 xlB = *(const u16x8*)(xlb + ((size_t)(srB & 0x1FFFFu) << 9));
      u16x8 erB = *(const u16x8*)(erb + ((size_t)(srB >> 17) << 9));
      f32x2 xa2[4], xb2[4];
      float pa = edge_accum(xlA, erA, xr2, at2, xa2);
      float pb = edge_accum(xlB, erB, xr2, at2, xb2);
      pa = dpp_red16(pa);
      pb = dpp_red16(pb);
      float wa = __expf(pa);
      float wb = __expf(pb);
      denom += wa + wb;
#pragma unroll
      for (int i = 0; i < 4; ++i) {
        acc2[i] += xa2[i] * wa;     // v_pk_fma_f32
        acc2[i] += xb2[i] * wb;
      }
    }
    // ---- tail: guarded pairs (at most 2 iterations) ----
    for (; e < e1; e += 2) {
      int ee = e + half;
      bool valid = ee < e1;
      unsigned sr = sorted[valid ? ee : e0];
      u16x8 xl8 = *(const u16x8*)(xlb + ((size_t)(sr & 0x1FFFFu) << 9));
      u16x8 er8 = *(const u16x8*)(erb + ((size_t)(sr >> 17) << 9));
      f32x2 x2[4];
      float p = edge_accum(xl8, er8, xr2, at2, x2);
      p = dpp_red16(p);
      float wgt = valid ? __expf(p) : 0.f;
      denom += wgt;
#pragma unroll
      for (int i = 0; i < 4; ++i) acc2[i] += x2[i] * wgt;
    }
    // combine the two edge-halves (same target, same head layout)
    denom += __shfl_xor(denom, 32, 64);
#pragma unroll
    for (int i = 0; i < 4; ++i) {
      acc2[i][0] += __shfl_xor(acc2[i][0], 32, 64);
      acc2[i][1] += __shfl_xor(acc2[i][1], 32, 64);
    }
    // normalize per head; fold the head-mean (x0.5) into the reciprocal
    float inv = 0.5f / (denom + 1e-16f);
    float o[8];
#pragma unroll
    for (int i = 0; i < 4; ++i) {
      o[2 * i] = acc2[i][0] * inv;
      o[2 * i + 1] = acc2[i][1] * inv;
    }
    // combine heads: lane sl (head0, d=8sl..) with lane sl^16 (head1, same d)
#pragma unroll
    for (int i = 0; i < 8; ++i) o[i] += __shfl_xor(o[i], 16, 64);
    if (lane < 16) {
      int t = t0 + ti;
      int d = sl * 8;
      float4 b0 = *(const float4*)(bias + d);
      float4 b1 = *(const float4*)(bias + d + 4);
      f32x4 s0 = (f32x4){o[0] + b0.x, o[1] + b0.y, o[2] + b0.z, o[3] + b0.w};
      f32x4 s1 = (f32x4){o[4] + b1.x, o[5] + b1.y, o[6] + b1.z, o[7] + b1.w};
      __builtin_nontemporal_store(s0, (f32x4*)(out + (size_t)t * D + d));
      __builtin_nontemporal_store(s1, (f32x4*)(out + (size_t)t * D + d + 4));
    }
  }
}

extern "C" void kernel_launch(void* const* d_in, const int* in_sizes, int n_in,
                              void* d_out, int out_size, void* d_ws, size_t ws_size,
                              hipStream_t stream) {
  const float* queries = (const float*)d_in[0];
  const float* entities = (const float*)d_in[1];
  const int* edge_index = (const int*)d_in[2];
  const float* relations = (const float*)d_in[3];
  const int* relation_index = (const int*)d_in[4];
  const int* batch = (const int*)d_in[5];
  const float* W_l = (const float*)d_in[6];
  const float* b_l = (const float*)d_in[7];
  const float* W_r = (const float*)d_in[8];
  const float* b_r = (const float*)d_in[9];
  const float* W_ea = (const float*)d_in[10];
  const float* att = (const float*)d_in[11];
  const float* bias = (const float*)d_in[12];
  const float* W_le = (const float*)d_in[13];
  const float* b_le = (const float*)d_in[14];

  float* out_node = (float*)d_out;
  float* out_edge = out_node + (size_t)N_ENT * D;

  char* base = (char*)d_ws;
  size_t off = 0;
  auto take = [&](size_t nbytes) -> void* {
    void* p = base + off;
    off += (nbytes + 255) & ~(size_t)255;
    return p;
  };
  unsigned short* x_l = (unsigned short*)take((size_t)NTOT * HD * sizeof(unsigned short)); // 51.2 MB
  unsigned short* x_r = (unsigned short*)take((size_t)NTOT * HD * sizeof(unsigned short)); // 51.2 MB
  unsigned short* e_rel = (unsigned short*)take((size_t)(RCOUNT + 1) * HD * sizeof(unsigned short));
  unsigned short* Wbf = (unsigned short*)take((size_t)512 * D * sizeof(unsigned short));   // 128 KB
  int* counts = (int*)take((size_t)CPAD * sizeof(int));                                    // padded to 100096
  int* offsets = (int*)take((size_t)(N_ENT + 1) * sizeof(int));
  unsigned* tr = (unsigned*)take((size_t)ETOT * sizeof(unsigned));                         // 2 MB
  unsigned* key = (unsigned*)take((size_t)ETOT * sizeof(unsigned));                        // 2 MB
  int* bsum = (int*)take(512 * sizeof(int));
  unsigned* sorted = (unsigned*)take((size_t)ETOT * sizeof(unsigned));                     // 2 MB

  hipMemsetAsync(counts, 0, (size_t)CPAD * sizeof(int), stream);
  k_prep<<<dim3(PREP_NB), dim3(256), 0, stream>>>(W_l, W_r, Wbf, relations, W_ea, W_le, b_le,
                                                  e_rel, out_edge);
  k_gemm_mfma<<<dim3(GEMM_NB + HIST_NB), dim3(256), 0, stream>>>(entities, queries, Wbf, b_l, b_r,
                                                                 x_l, x_r, edge_index, relation_index,
                                                                 batch, counts, tr, key);
  k_scan_a<<<dim3(SCAN_NB), dim3(256), 0, stream>>>(counts, bsum);
  k_scan_b<<<dim3(SCAN_NB), dim3(256), 0, stream>>>(counts, bsum, offsets);
  k_scatter<<<dim3(HIST_NB), dim3(256), 0, stream>>>(tr, key, offsets, sorted);
  k_edge<<<dim3(EDGE_NB), dim3(256), 0, stream>>>(x_l, x_r, e_rel, offsets, sorted, att, bias, out_node);
}

// Round 14
// 284.534 us; speedup vs baseline: 1.7889x; 1.0025x over previous
//
#include <hip/hip_runtime.h>
#include <math.h>

#define D 128
#define HD 256
#define N_ENT 100000
#define NBATCH 64
#define NTOT (N_ENT + NBATCH)   // 100064
#define RCOUNT 500
#define E_BASE 400000
#define ETOT (E_BASE + N_ENT)   // 500000
#define NEG 0.2f
#define SCAN_NB 391             // 391*256 = 100096 (counts padded)
#define CPAD (SCAN_NB * 256)

#define WCAST_NB 64
#define ZERO_NB SCAN_NB
#define REL_NB (RCOUNT + 1)
#define PREP_NB (WCAST_NB + ZERO_NB + REL_NB)   // 956

#define GEMM_NB ((NTOT + 63) / 64)              // 1564
#define HIST_NB ((ETOT + 255) / 256)            // 1954
#define SCAT_NB ((ETOT / 4 + 255) / 256)        // 489
#define EDGE_NB 6250                            // 25000 waves x 4 targets = 100000

typedef __attribute__((ext_vector_type(8))) short bf16x8;
typedef __attribute__((ext_vector_type(8))) unsigned short u16x8;
typedef __attribute__((ext_vector_type(4))) float f32x4;
typedef __attribute__((ext_vector_type(2))) float f32x2;

// hardware packed fp32->bf16 RNE (gfx950 v_cvt_pk_bf16_f32): lo -> [15:0], hi -> [31:16]
static __device__ __forceinline__ unsigned cvt_pk_bf16(float lo, float hi) {
  unsigned r;
  asm("v_cvt_pk_bf16_f32 %0, %1, %2" : "=v"(r) : "v"(lo), "v"(hi));
  return r;
}
static __device__ __forceinline__ unsigned short f2bf_hw(float f) {
  unsigned r;
  asm("v_cvt_pk_bf16_f32 %0, %1, %1" : "=v"(r) : "v"(f));
  return (unsigned short)r;
}
// decode 2 packed bf16 (one u32) -> 2 f32: 2 bit-ops total
static __device__ __forceinline__ f32x2 bfpair(unsigned u) {
  f32x2 r;
  r[0] = __builtin_bit_cast(float, u << 16);
  r[1] = __builtin_bit_cast(float, u & 0xffff0000u);
  return r;
}

// LDS-only barrier: syncs waves + drains LDS ops, but does NOT drain vmcnt --
// global stores stay in flight (HIP __syncthreads forces s_waitcnt vmcnt(0)).
static __device__ __forceinline__ void lds_barrier() {
  __builtin_amdgcn_sched_barrier(0);
  asm volatile("s_waitcnt lgkmcnt(0)" ::: "memory");
  __builtin_amdgcn_sched_barrier(0);
  __builtin_amdgcn_s_barrier();
  __builtin_amdgcn_sched_barrier(0);
}

// sum across each 16-lane row via DPP (bitwise-identical butterfly to shfl_xor 1/2/4/8):
// all full-rate VALU, no LDS.
static __device__ __forceinline__ float dpp_red16(float p) {
  int t;
  t = __builtin_amdgcn_update_dpp(0, __builtin_bit_cast(int, p), 0xB1, 0xF, 0xF, true);
  p += __builtin_bit_cast(float, t);
  t = __builtin_amdgcn_update_dpp(0, __builtin_bit_cast(int, p), 0x4E, 0xF, 0xF, true);
  p += __builtin_bit_cast(float, t);
  t = __builtin_amdgcn_update_dpp(0, __builtin_bit_cast(int, p), 0x141, 0xF, 0xF, true);
  p += __builtin_bit_cast(float, t);
  t = __builtin_amdgcn_update_dpp(0, __builtin_bit_cast(int, p), 0x140, 0xF, 0xF, true);
  p += __builtin_bit_cast(float, t);
  return p;
}

// ---------------- prep: Wbf cast | zero counts | e_rel + out_edge ----------------
__global__ __launch_bounds__(256) void k_prep(
    const float* __restrict__ W_l, const float* __restrict__ W_r,
    unsigned short* __restrict__ Wbf,
    const float* __restrict__ relations, const float* __restrict__ W_ea,
    const float* __restrict__ W_le, const float* __restrict__ b_le,
    unsigned short* __restrict__ e_rel, float* __restrict__ out_edge,
    int* __restrict__ counts) {
  __shared__ float relu_p[HD];
  int bx = blockIdx.x;
  int tid = threadIdx.x;
  if (bx < WCAST_NB) {
    int e4 = (bx * 256 + tid) * 4;
    int v = e4 >> 7;          // virtual row 0..511
    int k = e4 & 127;
    const float* src = (v < HD) ? (W_l + (size_t)v * D + k) : (W_r + (size_t)(v - HD) * D + k);
    float4 a = *(const float4*)src;
    uint2 p;
    p.x = cvt_pk_bf16(a.x, a.y);
    p.y = cvt_pk_bf16(a.z, a.w);
    *(uint2*)(Wbf + (size_t)v * D + k) = p;
    return;
  }
  if (bx < WCAST_NB + ZERO_NB) {   // zero counts in-dispatch: no separate memset op
    counts[(bx - WCAST_NB) * 256 + tid] = 0;
    return;
  }
  int r = bx - (WCAST_NB + ZERO_NB);   // 0..500
  int j = tid;
  const float* w = W_ea + (size_t)j * D;
  float acc = 0.f;
  if (r < RCOUNT) {
    const float* rel = relations + (size_t)r * D;
    for (int k = 0; k < D; k += 4) {
      float4 a = *(const float4*)(rel + k);
      float4 b = *(const float4*)(w + k);
      acc += a.x * b.x + a.y * b.y + a.z * b.z + a.w * b.w;
    }
  } else {  // all-ones rel_feat row -> row sums of W_ea
    for (int k = 0; k < D; k += 4) {
      float4 b = *(const float4*)(w + k);
      acc += b.x + b.y + b.z + b.w;
    }
  }
  e_rel[(size_t)r * HD + j] = f2bf_hw(acc);
  if (r < RCOUNT) {
    relu_p[j] = acc > 0.f ? acc : 0.f;
    __syncthreads();
    if (j < D) {
      const float* wl = W_le + (size_t)j * HD;
      float o = b_le[j];
      for (int k = 0; k < HD; k += 4) {
        float4 p4 = *(const float4*)(relu_p + k);
        float4 w4 = *(const float4*)(wl + k);
        o += p4.x * w4.x + p4.y * w4.y + p4.z * w4.z + p4.w * w4.w;
      }
      out_edge[(size_t)r * D + j] = o;
    }
  }
}

// ---------------- MFMA GEMM (64-row blocks, all 512 vcols) + fused edge histogram ----------------
#define LDA 136  // LDS row stride in ushort

__global__ __launch_bounds__(256) void k_gemm_mfma(
    const float* __restrict__ entities, const float* __restrict__ queries,
    const unsigned short* __restrict__ Wbf,
    const float* __restrict__ b_l, const float* __restrict__ b_r,
    unsigned short* __restrict__ x_l, unsigned short* __restrict__ x_r,
    const int* __restrict__ edge_index, const int* __restrict__ relation_index,
    const int* __restrict__ batch, int* __restrict__ counts,
    unsigned* __restrict__ tr, unsigned* __restrict__ key) {
  // single 17.4 KB buffer: stage-A tile, then (after afr hoist) reused as C staging.
  // halves LDS/block vs separate As/Cs -> 8 blocks/CU (wave cap) instead of 4.
  __shared__ unsigned short AsCs[64 * LDA];
  int tid = threadIdx.x;
  if (blockIdx.x >= GEMM_NB) {   // histogram blocks: count + per-edge (t,rank) and (s,r) packs
    int e = (blockIdx.x - GEMM_NB) * 256 + tid;
    if (e < ETOT) {
      int s, t, r;
      if (e < E_BASE) {
        s = edge_index[e];
        t = edge_index[E_BASE + e];
        r = relation_index[e];
      } else {
        int i = e - E_BASE;
        s = N_ENT + batch[i];
        t = i;
        r = RCOUNT;
      }
      int rk = atomicAdd(counts + t, 1);
      // NOTE (R11 lesson): do NOT add a second atomic to a low-cardinality array here.
      // 500K atomics -> 391 counters (~25 cache lines) line-serialize at L2: +240 us.
      tr[e] = (unsigned)t | ((unsigned)rk << 17);
      key[e] = (unsigned)s | ((unsigned)r << 17);
    }
    return;
  }
  int rb = blockIdx.x;          // 64-row tile

  // ---- stage A (fp32 -> bf16 via v_cvt_pk, plain cached loads), once ----
  {
    int rr = tid >> 2;                 // 0..63
    int part = (tid & 3) * 32;
    int row = rb * 64 + rr;
    const float* sp;
    if (row < N_ENT) sp = entities + (size_t)row * D;
    else if (row < NTOT) sp = queries + (size_t)(row - N_ENT) * D;
    else sp = entities;  // dummy; stores guarded
#pragma unroll
    for (int k = 0; k < 32; k += 8) {
      float4 a0 = *(const float4*)(sp + part + k);
      float4 a1 = *(const float4*)(sp + part + k + 4);
      uint4 p;
      p.x = cvt_pk_bf16(a0.x, a0.y);
      p.y = cvt_pk_bf16(a0.z, a0.w);
      p.z = cvt_pk_bf16(a1.x, a1.y);
      p.w = cvt_pk_bf16(a1.z, a1.w);
      *(uint4*)(&AsCs[rr * LDA + part + k]) = p;
    }
  }
  __syncthreads();

  int w = tid >> 6, lane = tid & 63;
  int wr = w >> 1, wc = w & 1;          // 2x2 wave grid per 128-col chunk
  int m = lane & 15, q8 = (lane >> 4) * 8;

  // ---- hoist A fragments to registers: after this, the LDS tile is DEAD as A ----
  bf16x8 afr[4][2];
#pragma unroll
  for (int k4 = 0; k4 < 4; k4++)
#pragma unroll
    for (int i = 0; i < 2; i++)
      afr[k4][i] = *(const bf16x8*)(&AsCs[(wr * 32 + i * 16 + m) * LDA + k4 * 32 + q8]);

  for (int ccv = 0; ccv < 4; ccv++) {   // virtual col chunks of 128 (0,1->x_l; 2,3->x_r)
    bool isL = ccv < 2;
    const float* bv = isL ? b_l : b_r;
    unsigned short* xdst = isL ? x_l : x_r;
    int cbase = (ccv & 1) * 128;

    f32x4 acc[2][4];
#pragma unroll
    for (int i = 0; i < 2; i++)
#pragma unroll
      for (int j = 0; j < 4; j++) acc[i][j] = (f32x4){0.f, 0.f, 0.f, 0.f};

    const unsigned short* wbase = Wbf + (size_t)(ccv * 128 + wc * 64 + m) * D;
#pragma unroll
    for (int k4 = 0; k4 < 4; k4++) {
      bf16x8 bfr[4];
#pragma unroll
      for (int j = 0; j < 4; j++)
        bfr[j] = *(const bf16x8*)(wbase + (size_t)j * 16 * D + k4 * 32 + q8);
#pragma unroll
      for (int i = 0; i < 2; i++)
#pragma unroll
        for (int j = 0; j < 4; j++)
          acc[i][j] = __builtin_amdgcn_mfma_f32_16x16x32_bf16(afr[k4][i], bfr[j], acc[i][j], 0, 0, 0);
    }

    // all waves' afr hoist reads (and prior chunk's C ds_reads) complete before
    // overwriting the buffer; global stores stay in flight (no vmcnt drain).
    lds_barrier();
    // acc -> LDS (row-major, +bias, bf16). C layout: col=lane&15, row=(lane>>4)*4+reg
#pragma unroll
    for (int j = 0; j < 4; j++) {
      int col = wc * 64 + j * 16 + m;
      float bb = bv[cbase + col];
#pragma unroll
      for (int i = 0; i < 2; i++) {
        int row0 = wr * 32 + i * 16 + (lane >> 4) * 4;
#pragma unroll
        for (int r = 0; r < 4; r++)
          AsCs[(row0 + r) * LDA + col] = f2bf_hw(acc[i][j][r] + bb);
      }
    }
    lds_barrier();  // C ds_writes visible to all waves
    // coalesced CACHED global store (R6: x_l/x_r LLC residency feeds k_edge's gathers)
#pragma unroll
    for (int it = 0; it < 4; it++) {
      int g = it * 256 + tid;
      int row = g >> 4, c8 = (g & 15) * 8;
      int grow = rb * 64 + row;
      if (grow < NTOT) {
        u16x8 v = *(const u16x8*)(&AsCs[row * LDA + c8]);
        *(u16x8*)(xdst + (size_t)grow * HD + cbase + c8) = v;
      }
    }
  }
}

// ---------------- scan part a: per-block sums of counts ----------------
__global__ __launch_bounds__(256) void k_scan_a(const int* __restrict__ counts, int* __restrict__ bsum) {
  __shared__ int sd[256];
  int tid = threadIdx.x;
  sd[tid] = counts[blockIdx.x * 256 + tid];
  __syncthreads();
  for (int off = 128; off > 0; off >>= 1) {
    if (tid < off) sd[tid] += sd[tid + off];
    __syncthreads();
  }
  if (tid == 0) bsum[blockIdx.x] = sd[0];
}

// ---------------- scan part b: lookback over bsum + local scan -> offsets ----------------
__global__ __launch_bounds__(256) void k_scan_b(
    const int* __restrict__ counts, const int* __restrict__ bsum,
    int* __restrict__ offsets) {
  __shared__ int s[256];
  int b = blockIdx.x, tid = threadIdx.x;
  int part = 0;
  if (tid < b) part += bsum[tid];
  if (tid + 256 < b) part += bsum[tid + 256];
  s[tid] = part;
  __syncthreads();
  for (int off = 128; off > 0; off >>= 1) {
    if (tid < off) s[tid] += s[tid + off];
    __syncthreads();
  }
  int pre_sum = s[0];
  __syncthreads();
  int v = counts[b * 256 + tid];
  s[tid] = v;
  __syncthreads();
  for (int off = 1; off < 256; off <<= 1) {
    int y = (tid >= off) ? s[tid - off] : 0;
    __syncthreads();
    s[tid] += y;
    __syncthreads();
  }
  int excl = pre_sum + s[tid] - v;
  int i = b * 256 + tid;
  if (i <= N_ENT) offsets[i] = excl;   // i==N_ENT -> ETOT
}

// atomic-free scatter, 4 edges/thread with uint4 loads of tr/key
__global__ __launch_bounds__(256) void k_scatter(
    const unsigned* __restrict__ tr, const unsigned* __restrict__ key,
    const int* __restrict__ offsets, unsigned* __restrict__ sorted) {
  int e4 = (blockIdx.x * 256 + threadIdx.x) * 4;
  if (e4 + 4 <= ETOT) {   // ETOT = 500000 = 4*125000, so the guard only trims the pad
    uint4 a = *(const uint4*)(tr + e4);
    uint4 k = *(const uint4*)(key + e4);
    sorted[offsets[a.x & 0x1FFFFu] + (a.x >> 17)] = k.x;
    sorted[offsets[a.y & 0x1FFFFu] + (a.y >> 17)] = k.y;
    sorted[offsets[a.z & 0x1FFFFu] + (a.z >> 17)] = k.z;
    sorted[offsets[a.w & 0x1FFFFu] + (a.w >> 17)] = k.w;
  } else {
    for (int e = e4; e < ETOT; ++e) {
      unsigned a = tr[e];
      sorted[offsets[a & 0x1FFFFu] + (a >> 17)] = key[e];
    }
  }
}

// one edge's elementwise work on this lane's 8 elems (4 f32-pairs -> v_pk_* ops):
// returns lane-partial logit; writes decoded x_l pair values for the later acc FMA.
static __device__ __forceinline__ float edge_accum(
    u16x8 xl8, u16x8 er8, const f32x2* __restrict__ xr2,
    const f32x2* __restrict__ at2, f32x2* __restrict__ x2) {
  uint4 xu = __builtin_bit_cast(uint4, xl8);
  uint4 eu = __builtin_bit_cast(uint4, er8);
  unsigned xw[4] = {xu.x, xu.y, xu.z, xu.w};
  unsigned ew[4] = {eu.x, eu.y, eu.z, eu.w};
  f32x2 p2 = (f32x2){0.f, 0.f};
#pragma unroll
  for (int i = 0; i < 4; ++i) {
    f32x2 x = bfpair(xw[i]);
    x2[i] = x;
    f32x2 z = (x + xr2[i]) + bfpair(ew[i]);
    f32x2 zn = z * NEG;
    z[0] = fmaxf(z[0], zn[0]);   // leaky_relu(z) == max(z, 0.2z)
    z[1] = fmaxf(z[1], zn[1]);
    p2 += z * at2[i];
  }
  return p2[0] + p2[1];
}

// ---------------- per-target aggregate: persistent waves, 4 targets/wave ----------------
// lanes 0-31 edge e, lanes 32-63 edge e+1; within 32: sl 0-15 head0, sl 16-31 head1.
__global__ __launch_bounds__(256) void k_edge(
    const unsigned short* __restrict__ x_l, const unsigned short* __restrict__ x_r,
    const unsigned short* __restrict__ e_rel, const int* __restrict__ offsets,
    const unsigned* __restrict__ sorted, const float* __restrict__ att,
    const float* __restrict__ bias, float* __restrict__ out) {
  int wv = threadIdx.x >> 6;
  int lane = threadIdx.x & 63;
  int half = lane >> 5;         // which edge of the pair
  int sl = lane & 31;
  int elem = sl * 8;            // head = sl>>4
  int t0 = (blockIdx.x * 4 + wv) * 4;   // 4 contiguous targets per wave

  const char* xlb = (const char*)x_l + elem * 2;   // per-lane gather bases
  const char* erb = (const char*)e_rel + elem * 2;

  f32x2 at2[4];
  {
    float4 a0 = *(const float4*)(att + elem);
    float4 a1 = *(const float4*)(att + elem + 4);
    at2[0] = (f32x2){a0.x, a0.y};
    at2[1] = (f32x2){a0.z, a0.w};
    at2[2] = (f32x2){a1.x, a1.y};
    at2[3] = (f32x2){a1.z, a1.w};
  }
  // all 5 edge-range boundaries for this wave in one 16B load + 1 scalar
  int4 ofs = *(const int4*)(offsets + t0);
  int eb[5];
  eb[0] = ofs.x; eb[1] = ofs.y; eb[2] = ofs.z; eb[3] = ofs.w;
  eb[4] = offsets[t0 + 4];

  u16x8 xr8 = __builtin_nontemporal_load((const u16x8*)(x_r + (size_t)t0 * HD + elem));

#pragma unroll
  for (int ti = 0; ti < 4; ++ti) {
    f32x2 xr2[4];
    {
      uint4 u = __builtin_bit_cast(uint4, xr8);
      xr2[0] = bfpair(u.x); xr2[1] = bfpair(u.y);
      xr2[2] = bfpair(u.z); xr2[3] = bfpair(u.w);
    }
    // prefetch next target's x_r row (t0+ti+1 <= 100000 < NTOT, always in-bounds)
    xr8 = __builtin_nontemporal_load((const u16x8*)(x_r + (size_t)(t0 + ti + 1) * HD + elem));

    int e0 = eb[ti], e1 = eb[ti + 1];
    f32x2 acc2[4];
    acc2[0] = acc2[1] = acc2[2] = acc2[3] = (f32x2){0.f, 0.f};
    float denom = 0.f;
    int e = e0;
    // ---- main: 4 valid edges per iter, two independent chains, no guards ----
    for (; e + 4 <= e1; e += 4) {
      unsigned srA = sorted[e + half];
      unsigned srB = sorted[e + 2 + half];
      u16x8 xlA = *(const u16x8*)(xlb + ((size_t)(srA & 0x1FFFFu) << 9));
      u16x8 erA = *(const u16x8*)(erb + ((size_t)(srA >> 17) << 9));
      u16x8 xlB = *(const u16x8*)(xlb + ((size_t)(srB & 0x1FFFFu) << 9));
      u16x8 erB = *(const u16x8*)(erb + ((size_t)(srB >> 17) << 9));
      f32x2 xa2[4], xb2[4];
      float pa = edge_accum(xlA, erA, xr2, at2, xa2);
      float pb = edge_accum(xlB, erB, xr2, at2, xb2);
      pa = dpp_red16(pa);
      pb = dpp_red16(pb);
      float wa = __expf(pa);
      float wb = __expf(pb);
      denom += wa + wb;
#pragma unroll
      for (int i = 0; i < 4; ++i) {
        acc2[i] += xa2[i] * wa;     // v_pk_fma_f32
        acc2[i] += xb2[i] * wb;
      }
    }
    // ---- tail: guarded pairs (at most 2 iterations) ----
    for (; e < e1; e += 2) {
      int ee = e + half;
      bool valid = ee < e1;
      unsigned sr = sorted[valid ? ee : e0];
      u16x8 xl8 = *(const u16x8*)(xlb + ((size_t)(sr & 0x1FFFFu) << 9));
      u16x8 er8 = *(const u16x8*)(erb + ((size_t)(sr >> 17) << 9));
      f32x2 x2[4];
      float p = edge_accum(xl8, er8, xr2, at2, x2);
      p = dpp_red16(p);
      float wgt = valid ? __expf(p) : 0.f;
      denom += wgt;
#pragma unroll
      for (int i = 0; i < 4; ++i) acc2[i] += x2[i] * wgt;
    }
    // combine the two edge-halves (same target, same head layout)
    denom += __shfl_xor(denom, 32, 64);
#pragma unroll
    for (int i = 0; i < 4; ++i) {
      acc2[i][0] += __shfl_xor(acc2[i][0], 32, 64);
      acc2[i][1] += __shfl_xor(acc2[i][1], 32, 64);
    }
    // normalize per head; fold the head-mean (x0.5) into the reciprocal
    float inv = 0.5f / (denom + 1e-16f);
    float o[8];
#pragma unroll
    for (int i = 0; i < 4; ++i) {
      o[2 * i] = acc2[i][0] * inv;
      o[2 * i + 1] = acc2[i][1] * inv;
    }
    // combine heads: lane sl (head0, d=8sl..) with lane sl^16 (head1, same d)
#pragma unroll
    for (int i = 0; i < 8; ++i) o[i] += __shfl_xor(o[i], 16, 64);
    if (lane < 16) {
      int t = t0 + ti;
      int d = sl * 8;
      float4 b0 = *(const float4*)(bias + d);
      float4 b1 = *(const float4*)(bias + d + 4);
      f32x4 s0 = (f32x4){o[0] + b0.x, o[1] + b0.y, o[2] + b0.z, o[3] + b0.w};
      f32x4 s1 = (f32x4){o[4] + b1.x, o[5] + b1.y, o[6] + b1.z, o[7] + b1.w};
      __builtin_nontemporal_store(s0, (f32x4*)(out + (size_t)t * D + d));
      __builtin_nontemporal_store(s1, (f32x4*)(out + (size_t)t * D + d + 4));
    }
  }
}

extern "C" void kernel_launch(void* const* d_in, const int* in_sizes, int n_in,
                              void* d_out, int out_size, void* d_ws, size_t ws_size,
                              hipStream_t stream) {
  const float* queries = (const float*)d_in[0];
  const float* entities = (const float*)d_in[1];
  const int* edge_index = (const int*)d_in[2];
  const float* relations = (const float*)d_in[3];
  const int* relation_index = (const int*)d_in[4];
  const int* batch = (const int*)d_in[5];
  const float* W_l = (const float*)d_in[6];
  const float* b_l = (const float*)d_in[7];
  const float* W_r = (const float*)d_in[8];
  const float* b_r = (const float*)d_in[9];
  const float* W_ea = (const float*)d_in[10];
  const float* att = (const float*)d_in[11];
  const float* bias = (const float*)d_in[12];
  const float* W_le = (const float*)d_in[13];
  const float* b_le = (const float*)d_in[14];

  float* out_node = (float*)d_out;
  float* out_edge = out_node + (size_t)N_ENT * D;

  char* base = (char*)d_ws;
  size_t off = 0;
  auto take = [&](size_t nbytes) -> void* {
    void* p = base + off;
    off += (nbytes + 255) & ~(size_t)255;
    return p;
  };
  unsigned short* x_l = (unsigned short*)take((size_t)NTOT * HD * sizeof(unsigned short)); // 51.2 MB
  unsigned short* x_r = (unsigned short*)take((size_t)NTOT * HD * sizeof(unsigned short)); // 51.2 MB
  unsigned short* e_rel = (unsigned short*)take((size_t)(RCOUNT + 1) * HD * sizeof(unsigned short));
  unsigned short* Wbf = (unsigned short*)take((size_t)512 * D * sizeof(unsigned short));   // 128 KB
  int* counts = (int*)take((size_t)CPAD * sizeof(int));                                    // padded to 100096
  int* offsets = (int*)take((size_t)(N_ENT + 1) * sizeof(int));
  unsigned* tr = (unsigned*)take((size_t)ETOT * sizeof(unsigned));                         // 2 MB
  unsigned* key = (unsigned*)take((size_t)ETOT * sizeof(unsigned));                        // 2 MB
  int* bsum = (int*)take(512 * sizeof(int));
  unsigned* sorted = (unsigned*)take((size_t)ETOT * sizeof(unsigned));                     // 2 MB

  k_prep<<<dim3(PREP_NB), dim3(256), 0, stream>>>(W_l, W_r, Wbf, relations, W_ea, W_le, b_le,
                                                  e_rel, out_edge, counts);
  k_gemm_mfma<<<dim3(GEMM_NB + HIST_NB), dim3(256), 0, stream>>>(entities, queries, Wbf, b_l, b_r,
                                                                 x_l, x_r, edge_index, relation_index,
                                                                 batch, counts, tr, key);
  k_scan_a<<<dim3(SCAN_NB), dim3(256), 0, stream>>>(counts, bsum);
  k_scan_b<<<dim3(SCAN_NB), dim3(256), 0, stream>>>(counts, bsum, offsets);
  k_scatter<<<dim3(SCAT_NB), dim3(256), 0, stream>>>(tr, key, offsets, sorted);
  k_edge<<<dim3(EDGE_NB), dim3(256), 0, stream>>>(x_l, x_r, e_rel, offsets, sorted, att, bias, out_node);
}